// Round 7
// baseline (115.177 us; speedup 1.0000x reference)
//
#include <hip/hip_runtime.h>
#include <math.h>

#define HIDDEN 256
#define BATCH 8192
#define NEGS 16
#define NSCORES (BATCH + BATCH * NEGS)  // 139264
#define PI2 6.28318530717958647692f

typedef unsigned int uv2 __attribute__((ext_vector_type(2)));

__device__ __forceinline__ float2 cmul(float2 a, float2 b) {
    return make_float2(fmaf(a.x, b.x, -a.y * b.y), fmaf(a.x, b.y, a.y * b.x));
}

__device__ __forceinline__ float xorf(float x, unsigned s) {
    return __uint_as_float(__float_as_uint(x) ^ s);
}

// DPP cross-lane (VALU): quad_perm xor1=0xB1, xor2=0x4E, row_mirror(xor15)=0x140
template<int C>
__device__ __forceinline__ float fdpp(float v) {
    return __uint_as_float((unsigned)__builtin_amdgcn_mov_dpp(
        (int)__float_as_uint(v), C, 0xf, 0xf, true));
}

// ds_swizzle (DS pipe): xor4=0x101F, xor8=0x201F
template<int IMM>
__device__ __forceinline__ float fswz(float v) {
    return __uint_as_float((unsigned)__builtin_amdgcn_ds_swizzle(
        (int)__float_as_uint(v), IMM));
}

// shfl_xor 32 via v_permlane32_swap (VALU). hi = (lane&32)!=0.
__device__ __forceinline__ float fpl32(float v, bool hi) {
    uv2 r = __builtin_amdgcn_permlane32_swap(__float_as_uint(v), __float_as_uint(v),
                                             false, false);
    return __uint_as_float(hi ? r.x : r.y);
}
// shfl_xor 16 via v_permlane16_swap (VALU). hi = (lane&16)!=0.
__device__ __forceinline__ float fpl16(float v, bool hi) {
    uv2 r = __builtin_amdgcn_permlane16_swap(__float_as_uint(v), __float_as_uint(v),
                                             false, false);
    return __uint_as_float(hi ? r.x : r.y);
}

// DIF radix-4 butterfly (verified in R4-R6)
__device__ __forceinline__ void bfly4(float2 a, float2 b, float2 c, float2 d,
                                      float2& u0, float2& u1, float2& u2, float2& u3) {
    float2 apc = make_float2(a.x + c.x, a.y + c.y);
    float2 amc = make_float2(a.x - c.x, a.y - c.y);
    float2 bpd = make_float2(b.x + d.x, b.y + d.y);
    float2 bmd = make_float2(b.x - d.x, b.y - d.y);
    u0 = make_float2(apc.x + bpd.x, apc.y + bpd.y);
    u2 = make_float2(apc.x - bpd.x, apc.y - bpd.y);
    u1 = make_float2(amc.x + bmd.y, amc.y - bmd.x);   // (a-c) - i(b-d)
    u3 = make_float2(amc.x - bmd.y, amc.y + bmd.x);   // (a-c) + i(b-d)
}

// xor63 shuffle of a float2: row_mirror(xor15) . permlane16(xor16) . permlane32(xor32)
__device__ __forceinline__ float2 shfl63(float2 v, bool hi16, bool hi32) {
    float x = fdpp<0x140>(v.x); x = fpl16(x, hi16); x = fpl32(x, hi32);
    float y = fdpp<0x140>(v.y); y = fpl16(y, hi16); y = fpl32(y, hi32);
    return make_float2(x, y);
}

__device__ __forceinline__ float term(float2 A, float2 B, float2 fr) {
    const float imAB = A.x * B.y + A.y * B.x;
    const float dmag = (B.x * B.x + B.y * B.y) - (A.x * A.x + A.y * A.y);
    return fmaf(fr.x, imAB, fr.y * dmag);
}

// Pre-DFT rel table in the score-FFT's natural bin order f = c + 4*bitrev6(lane).
__global__ __launch_bounds__(256) void rel_fft_kernel(
    const float* __restrict__ rel, float2* __restrict__ FrP)
{
    __shared__ float rrow[256];
    const int tid = threadIdx.x;
    const int ri = blockIdx.x;
    const int lane = tid & 63;
    rrow[tid] = rel[ri * 256 + tid];
    __syncthreads();

    float rn2 = 0.f;
    #pragma unroll
    for (int j = 0; j < 4; ++j) { float v = rrow[lane + 64 * j]; rn2 = fmaf(v, v, rn2); }
    #pragma unroll
    for (int m = 32; m >= 1; m >>= 1) rn2 += __shfl_xor(rn2, m);
    const float scale = rsqrtf(fmaxf(rn2, 1e-12f)) * (1.0f / 256.0f);

    const int c = tid >> 6;
    const int f = c + 4 * (int)(__brev((unsigned)lane) >> 26);

    float ang = -PI2 * (float)f * (1.0f / 256.0f);
    float2 ws = make_float2(__cosf(ang), __sinf(ang));
    float2 p = ws;
    #pragma unroll
    for (int u = 0; u < 6; ++u) p = cmul(p, p);    // ws^64
    float2 p2 = cmul(p, p);                        // ws^128
    float2 p3 = cmul(p2, p);                       // ws^192

    float2 w0 = make_float2(1.f, 0.f), w1 = p, w2 = p2, w3 = p3;
    float re0 = 0.f, im0 = 0.f, re1 = 0.f, im1 = 0.f;
    float re2 = 0.f, im2 = 0.f, re3 = 0.f, im3 = 0.f;
    #pragma unroll 4
    for (int k = 0; k < 64; ++k) {
        float v0 = rrow[k], v1 = rrow[k + 64], v2 = rrow[k + 128], v3 = rrow[k + 192];
        re0 = fmaf(v0, w0.x, re0); im0 = fmaf(v0, w0.y, im0);
        re1 = fmaf(v1, w1.x, re1); im1 = fmaf(v1, w1.y, im1);
        re2 = fmaf(v2, w2.x, re2); im2 = fmaf(v2, w2.y, im2);
        re3 = fmaf(v3, w3.x, re3); im3 = fmaf(v3, w3.y, im3);
        w0 = cmul(w0, ws); w1 = cmul(w1, ws); w2 = cmul(w2, ws); w3 = cmul(w3, ws);
    }
    const float re = (re0 + re1) + (re2 + re3);
    const float im = (im0 + im1) + (im2 + im3);
    FrP[ri * 256 + tid] = make_float2(re * (scale * 0.5f), im * (scale * 0.25f));
}

// One score per wave. FFT-256 fully in registers:
//   stage A: radix-4 across the 4 regs (stride 64) + W256^{L*k} twiddles
//   then 6 in-place radix-2 stages across lanes (strides 32,16,8,4,2,1):
//   xor32/xor16 = permlane swaps (VALU), xor8/xor4 = ds_swizzle, xor2/xor1 = DPP.
// Output: reg c, lane L holds bin f = c + 4*bitrev6(L).
// Pairing f<->256-f: for c!=0 partner at (L^63, 4-c) via shfl63; c=0 via tiny LDS.
__global__ __launch_bounds__(256, 8) void score_kernel(
    const int* __restrict__ pos_h, const int* __restrict__ pos_t, const int* __restrict__ pos_r,
    const int* __restrict__ neg_h, const int* __restrict__ neg_t, const int* __restrict__ neg_r,
    const float* __restrict__ ent, const float2* __restrict__ FrP,
    float* __restrict__ scores)
{
    __shared__ float2 c0buf[4][64];
    const int tid = threadIdx.x, wave = tid >> 6, lane = tid & 63;
    const int s = blockIdx.x * 4 + wave;

    const bool isp = s < BATCH;
    const int j = isp ? s : s - BATCH;
    const int hi = (isp ? pos_h : neg_h)[j];
    const int ti = (isp ? pos_t : neg_t)[j];
    const int ri = (isp ? pos_r : neg_r)[j];

    const float* __restrict__ hrow = ent + (long)hi * HIDDEN;
    const float* __restrict__ trow = ent + (long)ti * HIDDEN;
    const float2* __restrict__ fb = FrP + (long)ri * 256;

    float2 z[4], fr[4];
    #pragma unroll
    for (int u = 0; u < 4; ++u)
        z[u] = make_float2(hrow[lane + 64 * u], trow[lane + 64 * u]);
    #pragma unroll
    for (int u = 0; u < 4; ++u) fr[u] = fb[u * 64 + lane];

    const bool hi32 = (lane & 32) != 0, hi16 = (lane & 16) != 0;
    const unsigned sg32 = (unsigned)(lane & 32) << 26;
    const unsigned sg16 = (unsigned)(lane & 16) << 27;
    const unsigned sg8  = (unsigned)(lane & 8)  << 28;
    const unsigned sg4  = (unsigned)(lane & 4)  << 29;
    const unsigned sg2  = (unsigned)(lane & 2)  << 30;
    const unsigned sg1  = (unsigned)(lane & 1)  << 31;
    const bool ijswap = (lane & 3) == 3;

    // twiddles (neutralized to 1 for top lanes of each stage)
    float sa, ca;
    __sincosf(-PI2 * (1.0f / 256.0f) * (float)lane, &sa, &ca);
    const float2 w1 = make_float2(ca, sa);
    float s64, c64; __sincosf(-PI2 * (1.0f / 64.0f) * (float)(lane & 31), &s64, &c64);
    const float2 tw64 = hi32 ? make_float2(c64, s64) : make_float2(1.f, 0.f);
    float s32, c32; __sincosf(-PI2 * (1.0f / 32.0f) * (float)(lane & 15), &s32, &c32);
    const float2 tw32 = hi16 ? make_float2(c32, s32) : make_float2(1.f, 0.f);
    float s16, c16; __sincosf(-PI2 * (1.0f / 16.0f) * (float)(lane & 7), &s16, &c16);
    const float2 tw16 = (lane & 8) ? make_float2(c16, s16) : make_float2(1.f, 0.f);
    float s8, c8; __sincosf(-PI2 * (1.0f / 8.0f) * (float)(lane & 3), &s8, &c8);
    const float2 tw8 = (lane & 4) ? make_float2(c8, s8) : make_float2(1.f, 0.f);

    // ---- stage A: radix-4 across regs (stride 64), twiddle W256^{L*k}
    {
        float2 u0, u1, u2, u3;
        bfly4(z[0], z[1], z[2], z[3], u0, u1, u2, u3);
        const float2 w2 = cmul(w1, w1);
        const float2 w3 = cmul(w2, w1);
        z[0] = u0; z[1] = cmul(u1, w1); z[2] = cmul(u2, w2); z[3] = cmul(u3, w3);
    }

    // ---- 6 radix-2 ladder stages on lanes
    #pragma unroll
    for (int c = 0; c < 4; ++c) {
        float2 x = z[c];
        { // xor32, N=64
            float2 p = make_float2(fpl32(x.x, hi32), fpl32(x.y, hi32));
            x = cmul(make_float2(p.x + xorf(x.x, sg32), p.y + xorf(x.y, sg32)), tw64);
        }
        { // xor16, N=32
            float2 p = make_float2(fpl16(x.x, hi16), fpl16(x.y, hi16));
            x = cmul(make_float2(p.x + xorf(x.x, sg16), p.y + xorf(x.y, sg16)), tw32);
        }
        { // xor8, N=16
            float2 p = make_float2(fswz<0x201F>(x.x), fswz<0x201F>(x.y));
            x = cmul(make_float2(p.x + xorf(x.x, sg8), p.y + xorf(x.y, sg8)), tw16);
        }
        { // xor4, N=8
            float2 p = make_float2(fswz<0x101F>(x.x), fswz<0x101F>(x.y));
            x = cmul(make_float2(p.x + xorf(x.x, sg4), p.y + xorf(x.y, sg4)), tw8);
        }
        { // xor2, N=4: tw in {1, -i}
            float2 p = make_float2(fdpp<0x4E>(x.x), fdpp<0x4E>(x.y));
            float2 v = make_float2(p.x + xorf(x.x, sg2), p.y + xorf(x.y, sg2));
            x = ijswap ? make_float2(v.y, -v.x) : v;
        }
        { // xor1, N=2: tw = 1
            float2 p = make_float2(fdpp<0xB1>(x.x), fdpp<0xB1>(x.y));
            x = make_float2(p.x + xorf(x.x, sg1), p.y + xorf(x.y, sg1));
        }
        z[c] = x;
    }

    // ---- pairing + contraction. bin f = c + 4*m, m = bitrev6(L).
    const int m = (int)(__brev((unsigned)lane) >> 26);
    c0buf[wave][m] = z[0];
    // same-wave DS ops are in-order: partner slot written by this wave's ds_write
    const float2 B0 = c0buf[wave][(64 - m) & 63];
    const float2 B1 = shfl63(z[3], hi16, hi32);   // partner of reg1 bins
    const float2 B2 = shfl63(z[2], hi16, hi32);   // reg2 self-partnered across lanes
    const float2 B3 = shfl63(z[1], hi16, hi32);   // partner of reg3 bins

    float S = term(z[0], B0, fr[0]);
    S += term(z[1], B1, fr[1]);
    S += term(z[2], B2, fr[2]);
    S += term(z[3], B3, fr[3]);

    // wave xor-reduction (VALU/DPP + 2 swizzles + permlanes)
    S += fdpp<0xB1>(S);
    S += fdpp<0x4E>(S);
    S += fswz<0x101F>(S);
    S += fswz<0x201F>(S);
    S += fpl16(S, hi16);
    S += fpl32(S, hi32);

    if (lane == 0) scores[s] = -1.0f / (1.0f + __expf(-S));
}

// Deterministic single-block loss reduction (fully overwrites out[0]).
__global__ __launch_bounds__(1024) void loss_kernel(
    const float* __restrict__ scores, float* __restrict__ out)
{
    __shared__ float red[16];
    float sum = 0.f;
    for (int b = threadIdx.x; b < BATCH; b += 1024) {
        const float p = scores[b];
        const float* __restrict__ np = scores + BATCH + b * NEGS;
        float n = 0.f;
        #pragma unroll
        for (int j = 0; j < NEGS; ++j) n += np[j];
        n *= (1.0f / NEGS);
        sum += fmaxf(p - n + 1.0f, 0.0f);
    }
    #pragma unroll
    for (int m = 32; m >= 1; m >>= 1) sum += __shfl_xor(sum, m);
    const int wave = threadIdx.x >> 6;
    const int lane = threadIdx.x & 63;
    if (lane == 0) red[wave] = sum;
    __syncthreads();
    if (threadIdx.x < 16) {
        float v = red[threadIdx.x];
        #pragma unroll
        for (int m = 8; m >= 1; m >>= 1) v += __shfl_xor(v, m, 16);
        if (threadIdx.x == 0) out[0] = v;
    }
}

extern "C" void kernel_launch(void* const* d_in, const int* in_sizes, int n_in,
                              void* d_out, int out_size, void* d_ws, size_t ws_size,
                              hipStream_t stream) {
    (void)in_sizes; (void)n_in; (void)out_size; (void)ws_size;
    const int* pos_h = (const int*)d_in[0];
    const int* pos_t = (const int*)d_in[1];
    const int* pos_r = (const int*)d_in[2];
    const int* neg_h = (const int*)d_in[3];
    const int* neg_t = (const int*)d_in[4];
    const int* neg_r = (const int*)d_in[5];
    const float* ent = (const float*)d_in[6];
    const float* rel = (const float*)d_in[7];

    float2* FrP = (float2*)d_ws;                                    // 2,048,000 B
    float* scores = (float*)((char*)d_ws + 1000 * 256 * sizeof(float2));
    float* out = (float*)d_out;

    rel_fft_kernel<<<dim3(1000), dim3(256), 0, stream>>>(rel, FrP);
    score_kernel<<<dim3(NSCORES / 4), dim3(256), 0, stream>>>(
        pos_h, pos_t, pos_r, neg_h, neg_t, neg_r, ent, FrP, scores);
    loss_kernel<<<dim3(1), dim3(1024), 0, stream>>>(scores, out);
}

// Round 8
// 83.898 us; speedup vs baseline: 1.3728x; 1.3728x over previous
//
#include <hip/hip_runtime.h>
#include <math.h>

#define HIDDEN 256
#define BATCH 8192
#define NEGS 16
#define NSCORES (BATCH + BATCH * NEGS)  // 139264
#define PI2 6.28318530717958647692f

__device__ __forceinline__ float2 cmul(float2 a, float2 b) {
    return make_float2(fmaf(a.x, b.x, -a.y * b.y), fmaf(a.x, b.y, a.y * b.x));
}
__device__ __forceinline__ float2 cmulc(float2 a, float cx, float cy) {
    return make_float2(fmaf(a.x, cx, -a.y * cy), fmaf(a.x, cy, a.y * cx));
}
__device__ __forceinline__ float2 mulnegi(float2 a) { return make_float2(a.y, -a.x); }

// DPP cross-lane (VALU): quad_perm xor1=0xB1, xor2=0x4E, row_mirror=0x140
template<int C>
__device__ __forceinline__ float fdpp(float v) {
    return __uint_as_float((unsigned)__builtin_amdgcn_mov_dpp(
        (int)__float_as_uint(v), C, 0xf, 0xf, true));
}
// ds_swizzle: xor4=0x101F, xor8=0x201F
template<int IMM>
__device__ __forceinline__ float fswz(float v) {
    return __uint_as_float((unsigned)__builtin_amdgcn_ds_swizzle(
        (int)__float_as_uint(v), IMM));
}

// radix-4 DIF butterfly: u_k = DFT4 at freq k (W4 = -i)
__device__ __forceinline__ void bfly4(float2 a, float2 b, float2 c, float2 d,
                                      float2& u0, float2& u1, float2& u2, float2& u3) {
    float2 apc = make_float2(a.x + c.x, a.y + c.y);
    float2 amc = make_float2(a.x - c.x, a.y - c.y);
    float2 bpd = make_float2(b.x + d.x, b.y + d.y);
    float2 bmd = make_float2(b.x - d.x, b.y - d.y);
    u0 = make_float2(apc.x + bpd.x, apc.y + bpd.y);
    u2 = make_float2(apc.x - bpd.x, apc.y - bpd.y);
    u1 = make_float2(amc.x + bmd.y, amc.y - bmd.x);   // (a-c) - i(b-d)
    u3 = make_float2(amc.x - bmd.y, amc.y + bmd.x);   // (a-c) + i(b-d)
}

// In-register 16-point complex DFT (DIF radix-4), in natural-order in/out.
// Verified by delta-function algebra: z[f] = sum_n z_in[n] W16^{nf}.
__device__ __forceinline__ void fft16(float2 z[16]) {
    const float R  = 0.70710678118654752440f;
    const float C1 = 0.92387953251128675613f;
    const float S1 = 0.38268343236508977173f;
    #pragma unroll
    for (int p = 0; p < 4; ++p) {
        float2 u0, u1, u2, u3;
        bfly4(z[p], z[p+4], z[p+8], z[p+12], u0, u1, u2, u3);
        z[p] = u0; z[p+4] = u1; z[p+8] = u2; z[p+12] = u3;  // u_k[p] at z[4k+p]
    }
    // z[4k+p] *= W16^{pk}
    z[5]  = cmulc(z[5],  C1, -S1);   // W1
    z[6]  = cmulc(z[6],  R,  -R );   // W2
    z[7]  = cmulc(z[7],  S1, -C1);   // W3
    z[9]  = cmulc(z[9],  R,  -R );   // W2
    z[10] = mulnegi(z[10]);          // W4
    z[11] = cmulc(z[11], -R, -R );   // W6
    z[13] = cmulc(z[13], S1, -C1);   // W3
    z[14] = cmulc(z[14], -R, -R );   // W6
    z[15] = cmulc(z[15], -C1, S1);   // W9
    float2 o[16];
    #pragma unroll
    for (int k = 0; k < 4; ++k) {
        float2 v0, v1, v2, v3;
        bfly4(z[4*k], z[4*k+1], z[4*k+2], z[4*k+3], v0, v1, v2, v3);
        o[k] = v0; o[k+4] = v1; o[k+8] = v2; o[k+12] = v3;  // Y[k+4j]
    }
    #pragma unroll
    for (int i = 0; i < 16; ++i) z[i] = o[i];
}

// Pre-DFT rel table, natural bin order: FrP[ri*256 + f] =
//   ( Re(Fr_f)*s/2 , Im(Fr_f)*s/4 ),  s = 1/(256*||r||)
__global__ __launch_bounds__(256) void rel_fft_kernel(
    const float* __restrict__ rel, float2* __restrict__ FrP)
{
    __shared__ float rrow[256];
    const int tid = threadIdx.x;
    const int ri = blockIdx.x;
    const int lane = tid & 63;
    rrow[tid] = rel[ri * 256 + tid];
    __syncthreads();

    float rn2 = 0.f;
    #pragma unroll
    for (int j = 0; j < 4; ++j) { float v = rrow[lane + 64 * j]; rn2 = fmaf(v, v, rn2); }
    #pragma unroll
    for (int m = 32; m >= 1; m >>= 1) rn2 += __shfl_xor(rn2, m);
    const float scale = rsqrtf(fmaxf(rn2, 1e-12f)) * (1.0f / 256.0f);

    const int f = tid;
    float ang = -PI2 * (float)f * (1.0f / 256.0f);
    float2 ws = make_float2(__cosf(ang), __sinf(ang));
    float2 p = ws;
    #pragma unroll
    for (int u = 0; u < 6; ++u) p = cmul(p, p);    // ws^64
    float2 p2 = cmul(p, p);
    float2 p3 = cmul(p2, p);

    float2 w0 = make_float2(1.f, 0.f), w1 = p, w2 = p2, w3 = p3;
    float re0 = 0.f, im0 = 0.f, re1 = 0.f, im1 = 0.f;
    float re2 = 0.f, im2 = 0.f, re3 = 0.f, im3 = 0.f;
    #pragma unroll 4
    for (int k = 0; k < 64; ++k) {
        float v0 = rrow[k], v1 = rrow[k + 64], v2 = rrow[k + 128], v3 = rrow[k + 192];
        re0 = fmaf(v0, w0.x, re0); im0 = fmaf(v0, w0.y, im0);
        re1 = fmaf(v1, w1.x, re1); im1 = fmaf(v1, w1.y, im1);
        re2 = fmaf(v2, w2.x, re2); im2 = fmaf(v2, w2.y, im2);
        re3 = fmaf(v3, w3.x, re3); im3 = fmaf(v3, w3.y, im3);
        w0 = cmul(w0, ws); w1 = cmul(w1, ws); w2 = cmul(w2, ws); w3 = cmul(w3, ws);
    }
    const float re = (re0 + re1) + (re2 + re3);
    const float im = (im0 + im1) + (im2 + im3);
    FrP[ri * 256 + f] = make_float2(re * (scale * 0.5f), im * (scale * 0.25f));
}

// 16 lanes per score, 4 scores per wave, 16 scores per block.
// Four-step FFT-256: z[n1] = x[16 n1 + L] (reg n1, lane L=n2);
//   fft16 over regs -> X1[f1]; *= W256^{L f1}; LDS transpose (lane L picks
//   row digit sig(L)); fft16 over regs -> Z[f2] = X[sig(L) + 16 f2].
// sig chosen so bin-pairing f <-> 256-f is lane row_mirror: sig(15-L) = 16-sig(L).
__global__ __launch_bounds__(256, 4) void score_kernel(
    const int* __restrict__ pos_h, const int* __restrict__ pos_t, const int* __restrict__ pos_r,
    const int* __restrict__ neg_h, const int* __restrict__ neg_t, const int* __restrict__ neg_r,
    const float* __restrict__ ent, const float2* __restrict__ FrP,
    float* __restrict__ scores)
{
    __shared__ float2 T[16][272];   // 16 groups x (16 rows x 17 padded)
    const int tid = threadIdx.x;
    const int gb = tid >> 4;        // group in block (0..15)
    const int L = tid & 15;
    const int s = blockIdx.x * 16 + gb;

    const bool isp = s < BATCH;
    const int jj = isp ? s : s - BATCH;
    const int hi = (isp ? pos_h : neg_h)[jj];
    const int ti = (isp ? pos_t : neg_t)[jj];
    const int ri = (isp ? pos_r : neg_r)[jj];

    const float* __restrict__ hrow = ent + (long)hi * HIDDEN;
    const float* __restrict__ trow = ent + (long)ti * HIDDEN;

    float2 z[16];
    #pragma unroll
    for (int n1 = 0; n1 < 16; ++n1)
        z[n1] = make_float2(hrow[16 * n1 + L], trow[16 * n1 + L]);

    fft16(z);   // over n1 -> digit f1 in regs

    // twiddle W256^{L*f1}
    float sw, cw;
    __sincosf(-PI2 * (1.0f / 256.0f) * (float)L, &sw, &cw);
    {
        const float2 w = make_float2(cw, sw);
        float2 wp = w;
        z[1] = cmul(z[1], wp);
        #pragma unroll
        for (int f1 = 2; f1 < 16; ++f1) { wp = cmul(wp, w); z[f1] = cmul(z[f1], wp); }
    }

    // transpose write: T[gb][L*17 + f1]
    #pragma unroll
    for (int f1 = 0; f1 < 16; ++f1) T[gb][L * 17 + f1] = z[f1];

    // lane <-> f1 digit assignment sigma
    const int sig = (L == 0) ? 0 : (L == 15 ? 8 : (L < 8 ? L : L + 1));

    // fr loads (bin f = sig + 16*f2), issued to overlap with transpose+fft
    const float2* __restrict__ fb = FrP + (long)ri * 256 + sig;
    float2 fr[16];
    #pragma unroll
    for (int f2 = 0; f2 < 16; ++f2) fr[f2] = fb[16 * f2];

    __builtin_amdgcn_wave_barrier();   // keep ds_reads after ds_writes

    // transpose read: z[n2] = T[gb][n2*17 + sig]
    #pragma unroll
    for (int n2 = 0; n2 < 16; ++n2) z[n2] = T[gb][n2 * 17 + sig];

    fft16(z);   // over n2 -> Z[f2] = X[sig + 16 f2]

    const bool isL0 = (L == 0), isL15 = (L == 15);
    float S = 0.f;
    #pragma unroll
    for (int f2 = 0; f2 < 16; ++f2) {
        // partner of (lane, f2): mirror lane, reg 15-f2 (lanes 1..14);
        // lane 0: own reg (16-f2)&15; lane 15: own reg 15-f2.
        float2 src = z[15 - f2];
        float2 Bm = make_float2(fdpp<0x140>(src.x), fdpp<0x140>(src.y));
        float2 own0 = z[(16 - f2) & 15];
        float2 B;
        B.x = isL0 ? own0.x : (isL15 ? src.x : Bm.x);
        B.y = isL0 ? own0.y : (isL15 ? src.y : Bm.y);
        const float2 A = z[f2];
        const float imAB = A.x * B.y + A.y * B.x;
        const float dmag = (B.x * B.x + B.y * B.y) - (A.x * A.x + A.y * A.y);
        S = fmaf(fr[f2].x, imAB, fmaf(fr[f2].y, dmag, S));
    }

    // reduce across the 16-lane group
    S += fdpp<0xB1>(S);
    S += fdpp<0x4E>(S);
    S += fswz<0x101F>(S);
    S += fswz<0x201F>(S);

    if (L == 0) scores[s] = -1.0f / (1.0f + __expf(-S));
}

// Deterministic single-block loss reduction (fully overwrites out[0]).
__global__ __launch_bounds__(1024) void loss_kernel(
    const float* __restrict__ scores, float* __restrict__ out)
{
    __shared__ float red[16];
    float sum = 0.f;
    for (int b = threadIdx.x; b < BATCH; b += 1024) {
        const float p = scores[b];
        const float* __restrict__ np = scores + BATCH + b * NEGS;
        float n = 0.f;
        #pragma unroll
        for (int j = 0; j < NEGS; ++j) n += np[j];
        n *= (1.0f / NEGS);
        sum += fmaxf(p - n + 1.0f, 0.0f);
    }
    #pragma unroll
    for (int m = 32; m >= 1; m >>= 1) sum += __shfl_xor(sum, m);
    const int wave = threadIdx.x >> 6;
    const int lane = threadIdx.x & 63;
    if (lane == 0) red[wave] = sum;
    __syncthreads();
    if (threadIdx.x < 16) {
        float v = red[threadIdx.x];
        #pragma unroll
        for (int m = 8; m >= 1; m >>= 1) v += __shfl_xor(v, m, 16);
        if (threadIdx.x == 0) out[0] = v;
    }
}

extern "C" void kernel_launch(void* const* d_in, const int* in_sizes, int n_in,
                              void* d_out, int out_size, void* d_ws, size_t ws_size,
                              hipStream_t stream) {
    (void)in_sizes; (void)n_in; (void)out_size; (void)ws_size;
    const int* pos_h = (const int*)d_in[0];
    const int* pos_t = (const int*)d_in[1];
    const int* pos_r = (const int*)d_in[2];
    const int* neg_h = (const int*)d_in[3];
    const int* neg_t = (const int*)d_in[4];
    const int* neg_r = (const int*)d_in[5];
    const float* ent = (const float*)d_in[6];
    const float* rel = (const float*)d_in[7];

    float2* FrP = (float2*)d_ws;                                    // 2,048,000 B
    float* scores = (float*)((char*)d_ws + 1000 * 256 * sizeof(float2));
    float* out = (float*)d_out;

    rel_fft_kernel<<<dim3(1000), dim3(256), 0, stream>>>(rel, FrP);
    score_kernel<<<dim3(NSCORES / 16), dim3(256), 0, stream>>>(
        pos_h, pos_t, pos_r, neg_h, neg_t, neg_r, ent, FrP, scores);
    loss_kernel<<<dim3(1), dim3(1024), 0, stream>>>(scores, out);
}

// Round 9
// 77.264 us; speedup vs baseline: 1.4907x; 1.0859x over previous
//
#include <hip/hip_runtime.h>
#include <math.h>

#define HIDDEN 256
#define BATCH 8192
#define NEGS 16
#define NSCORES (BATCH + BATCH * NEGS)  // 139264
#define PI2 6.28318530717958647692f

__device__ __forceinline__ float2 cmul(float2 a, float2 b) {
    return make_float2(fmaf(a.x, b.x, -a.y * b.y), fmaf(a.x, b.y, a.y * b.x));
}
__device__ __forceinline__ float2 cmulc(float2 a, float cx, float cy) {
    return make_float2(fmaf(a.x, cx, -a.y * cy), fmaf(a.x, cy, a.y * cx));
}
__device__ __forceinline__ float2 mulnegi(float2 a) { return make_float2(a.y, -a.x); }

// DPP cross-lane (VALU): quad_perm xor1=0xB1, xor2=0x4E, row_mirror=0x140
template<int C>
__device__ __forceinline__ float fdpp(float v) {
    return __uint_as_float((unsigned)__builtin_amdgcn_mov_dpp(
        (int)__float_as_uint(v), C, 0xf, 0xf, true));
}
// ds_swizzle: xor4=0x101F, xor8=0x201F
template<int IMM>
__device__ __forceinline__ float fswz(float v) {
    return __uint_as_float((unsigned)__builtin_amdgcn_ds_swizzle(
        (int)__float_as_uint(v), IMM));
}

// radix-4 DIF butterfly: u_k = DFT4 at freq k (W4 = -i)
__device__ __forceinline__ void bfly4(float2 a, float2 b, float2 c, float2 d,
                                      float2& u0, float2& u1, float2& u2, float2& u3) {
    float2 apc = make_float2(a.x + c.x, a.y + c.y);
    float2 amc = make_float2(a.x - c.x, a.y - c.y);
    float2 bpd = make_float2(b.x + d.x, b.y + d.y);
    float2 bmd = make_float2(b.x - d.x, b.y - d.y);
    u0 = make_float2(apc.x + bpd.x, apc.y + bpd.y);
    u2 = make_float2(apc.x - bpd.x, apc.y - bpd.y);
    u1 = make_float2(amc.x + bmd.y, amc.y - bmd.x);   // (a-c) - i(b-d)
    u3 = make_float2(amc.x - bmd.y, amc.y + bmd.x);   // (a-c) + i(b-d)
}

// In-register 16-point complex DFT (DIF radix-4), natural-order in/out.
__device__ __forceinline__ void fft16(float2 z[16]) {
    const float R  = 0.70710678118654752440f;
    const float C1 = 0.92387953251128675613f;
    const float S1 = 0.38268343236508977173f;
    #pragma unroll
    for (int p = 0; p < 4; ++p) {
        float2 u0, u1, u2, u3;
        bfly4(z[p], z[p+4], z[p+8], z[p+12], u0, u1, u2, u3);
        z[p] = u0; z[p+4] = u1; z[p+8] = u2; z[p+12] = u3;
    }
    z[5]  = cmulc(z[5],  C1, -S1);
    z[6]  = cmulc(z[6],  R,  -R );
    z[7]  = cmulc(z[7],  S1, -C1);
    z[9]  = cmulc(z[9],  R,  -R );
    z[10] = mulnegi(z[10]);
    z[11] = cmulc(z[11], -R, -R );
    z[13] = cmulc(z[13], S1, -C1);
    z[14] = cmulc(z[14], -R, -R );
    z[15] = cmulc(z[15], -C1, S1);
    float2 o[16];
    #pragma unroll
    for (int k = 0; k < 4; ++k) {
        float2 v0, v1, v2, v3;
        bfly4(z[4*k], z[4*k+1], z[4*k+2], z[4*k+3], v0, v1, v2, v3);
        o[k] = v0; o[k+4] = v1; o[k+8] = v2; o[k+12] = v3;
    }
    #pragma unroll
    for (int i = 0; i < 16; ++i) z[i] = o[i];
}

// Pre-DFT rel table, natural bin order: FrP[ri*256 + f] =
//   ( Re(Fr_f)*s/2 , Im(Fr_f)*s/4 ),  s = 1/(256*||r||)
__global__ __launch_bounds__(256) void rel_fft_kernel(
    const float* __restrict__ rel, float2* __restrict__ FrP)
{
    __shared__ float rrow[256];
    const int tid = threadIdx.x;
    const int ri = blockIdx.x;
    const int lane = tid & 63;
    rrow[tid] = rel[ri * 256 + tid];
    __syncthreads();

    float rn2 = 0.f;
    #pragma unroll
    for (int j = 0; j < 4; ++j) { float v = rrow[lane + 64 * j]; rn2 = fmaf(v, v, rn2); }
    #pragma unroll
    for (int m = 32; m >= 1; m >>= 1) rn2 += __shfl_xor(rn2, m);
    const float scale = rsqrtf(fmaxf(rn2, 1e-12f)) * (1.0f / 256.0f);

    const int f = tid;
    float ang = -PI2 * (float)f * (1.0f / 256.0f);
    float2 ws = make_float2(__cosf(ang), __sinf(ang));
    float2 p = ws;
    #pragma unroll
    for (int u = 0; u < 6; ++u) p = cmul(p, p);    // ws^64
    float2 p2 = cmul(p, p);
    float2 p3 = cmul(p2, p);

    float2 w0 = make_float2(1.f, 0.f), w1 = p, w2 = p2, w3 = p3;
    float re0 = 0.f, im0 = 0.f, re1 = 0.f, im1 = 0.f;
    float re2 = 0.f, im2 = 0.f, re3 = 0.f, im3 = 0.f;
    #pragma unroll 4
    for (int k = 0; k < 64; ++k) {
        float v0 = rrow[k], v1 = rrow[k + 64], v2 = rrow[k + 128], v3 = rrow[k + 192];
        re0 = fmaf(v0, w0.x, re0); im0 = fmaf(v0, w0.y, im0);
        re1 = fmaf(v1, w1.x, re1); im1 = fmaf(v1, w1.y, im1);
        re2 = fmaf(v2, w2.x, re2); im2 = fmaf(v2, w2.y, im2);
        re3 = fmaf(v3, w3.x, re3); im3 = fmaf(v3, w3.y, im3);
        w0 = cmul(w0, ws); w1 = cmul(w1, ws); w2 = cmul(w2, ws); w3 = cmul(w3, ws);
    }
    const float re = (re0 + re1) + (re2 + re3);
    const float im = (im0 + im1) + (im2 + im3);
    FrP[ri * 256 + f] = make_float2(re * (scale * 0.5f), im * (scale * 0.25f));
}

#define RS 18                 // transpose row stride (float2): 144B, 16B-aligned
#define GS (16 * RS + 2)      // group stride 290 float2 -> 4-bank stagger

// 16 lanes per score, 4 scores per wave, 16 scores per block.
// Four-step FFT-256: z[n1] = x[16 n1 + L]; fft16 over regs -> f1;
// *= W256^{L f1}; LDS transpose M[n2][f1] (b128 writes, row stride 18);
// lane picks row digit sig; fft16 -> Z[f2] = X[sig + 16 f2].
// sig chosen so bin-pairing f <-> 256-f is lane row_mirror: sig(15-L)=16-sig(L).
__global__ __launch_bounds__(256, 4) void score_kernel(
    const int* __restrict__ pos_h, const int* __restrict__ pos_t, const int* __restrict__ pos_r,
    const int* __restrict__ neg_h, const int* __restrict__ neg_t, const int* __restrict__ neg_r,
    const float* __restrict__ ent, const float2* __restrict__ FrP,
    float* __restrict__ scores)
{
    __shared__ __align__(16) float2 T[16 * GS];
    const int tid = threadIdx.x;
    const int gb = tid >> 4;        // group in block (0..15)
    const int L = tid & 15;
    const int s = blockIdx.x * 16 + gb;

    const bool isp = s < BATCH;
    const int jj = isp ? s : s - BATCH;
    const int hi = (isp ? pos_h : neg_h)[jj];
    const int ti = (isp ? pos_t : neg_t)[jj];
    const int ri = (isp ? pos_r : neg_r)[jj];

    const float* __restrict__ hrow = ent + (long)hi * HIDDEN;
    const float* __restrict__ trow = ent + (long)ti * HIDDEN;

    float2 z[16];
    #pragma unroll
    for (int n1 = 0; n1 < 16; ++n1)
        z[n1] = make_float2(hrow[16 * n1 + L], trow[16 * n1 + L]);

    fft16(z);   // over n1 -> digit f1 in regs

    // twiddle W256^{L*f1}
    float sw, cw;
    __sincosf(-PI2 * (1.0f / 256.0f) * (float)L, &sw, &cw);
    {
        const float2 w = make_float2(cw, sw);
        float2 wp = w;
        z[1] = cmul(z[1], wp);
        #pragma unroll
        for (int f1 = 2; f1 < 16; ++f1) { wp = cmul(wp, w); z[f1] = cmul(z[f1], wp); }
    }

    // transpose write: row L (=n2), contiguous f1 -> 8 x ds_write_b128
    float2* __restrict__ Mg = T + gb * GS;
    {
        float4* __restrict__ wp4 = (float4*)(Mg + L * RS);
        #pragma unroll
        for (int j = 0; j < 8; ++j)
            wp4[j] = make_float4(z[2*j].x, z[2*j].y, z[2*j+1].x, z[2*j+1].y);
    }

    // lane <-> f1 digit assignment sigma
    const int sig = (L == 0) ? 0 : (L == 15 ? 8 : (L < 8 ? L : L + 1));

    // fr loads (bin f = sig + 16*f2); issued here to hide L2 latency under fft2
    const float2* __restrict__ fb = FrP + (long)ri * 256 + sig;
    float2 fr[16];
    #pragma unroll
    for (int f2 = 0; f2 < 16; ++f2) fr[f2] = fb[16 * f2];

    __builtin_amdgcn_wave_barrier();   // keep ds_reads after ds_writes

    // transpose read: z[n2] = M[n2][sig]
    #pragma unroll
    for (int n2 = 0; n2 < 16; ++n2) z[n2] = Mg[n2 * RS + sig];

    fft16(z);   // over n2 -> Z[f2] = X[sig + 16 f2]

    const bool isL0 = (L == 0), isL15 = (L == 15);
    float S = 0.f;
    #pragma unroll
    for (int f2 = 0; f2 < 16; ++f2) {
        // partner of (lane, f2): mirror lane, reg 15-f2 (lanes 1..14);
        // lane 0: own reg (16-f2)&15; lane 15: own reg 15-f2.
        float2 src = z[15 - f2];
        float2 Bm = make_float2(fdpp<0x140>(src.x), fdpp<0x140>(src.y));
        float2 own0 = z[(16 - f2) & 15];
        float2 B;
        B.x = isL0 ? own0.x : (isL15 ? src.x : Bm.x);
        B.y = isL0 ? own0.y : (isL15 ? src.y : Bm.y);
        const float2 A = z[f2];
        const float imAB = A.x * B.y + A.y * B.x;
        const float dmag = (B.x * B.x + B.y * B.y) - (A.x * A.x + A.y * A.y);
        S = fmaf(fr[f2].x, imAB, fmaf(fr[f2].y, dmag, S));
    }

    // reduce across the 16-lane group
    S += fdpp<0xB1>(S);
    S += fdpp<0x4E>(S);
    S += fswz<0x101F>(S);
    S += fswz<0x201F>(S);

    if (L == 0) scores[s] = -1.0f / (1.0f + __expf(-S));
}

// Stage 1: 32 blocks x 256 threads, one batch row per thread -> partial[32]
__global__ __launch_bounds__(256) void loss1_kernel(
    const float* __restrict__ scores, float* __restrict__ partial)
{
    __shared__ float red[4];
    const int b = blockIdx.x * 256 + threadIdx.x;
    const float p = scores[b];
    const float* __restrict__ np = scores + BATCH + b * NEGS;
    float n = 0.f;
    #pragma unroll
    for (int j = 0; j < NEGS; ++j) n += np[j];
    n *= (1.0f / NEGS);
    float v = fmaxf(p - n + 1.0f, 0.0f);
    #pragma unroll
    for (int m = 32; m >= 1; m >>= 1) v += __shfl_xor(v, m);
    const int wave = threadIdx.x >> 6, lane = threadIdx.x & 63;
    if (lane == 0) red[wave] = v;
    __syncthreads();
    if (threadIdx.x == 0)
        partial[blockIdx.x] = (red[0] + red[1]) + (red[2] + red[3]);
}

// Stage 2: one wave sums the 32 partials (deterministic, overwrites out[0]).
__global__ __launch_bounds__(64) void loss2_kernel(
    const float* __restrict__ partial, float* __restrict__ out)
{
    const int lane = threadIdx.x;
    float v = (lane < 32) ? partial[lane] : 0.f;
    #pragma unroll
    for (int m = 32; m >= 1; m >>= 1) v += __shfl_xor(v, m);
    if (lane == 0) out[0] = v;
}

extern "C" void kernel_launch(void* const* d_in, const int* in_sizes, int n_in,
                              void* d_out, int out_size, void* d_ws, size_t ws_size,
                              hipStream_t stream) {
    (void)in_sizes; (void)n_in; (void)out_size; (void)ws_size;
    const int* pos_h = (const int*)d_in[0];
    const int* pos_t = (const int*)d_in[1];
    const int* pos_r = (const int*)d_in[2];
    const int* neg_h = (const int*)d_in[3];
    const int* neg_t = (const int*)d_in[4];
    const int* neg_r = (const int*)d_in[5];
    const float* ent = (const float*)d_in[6];
    const float* rel = (const float*)d_in[7];

    float2* FrP = (float2*)d_ws;                                    // 2,048,000 B
    float* scores = (float*)((char*)d_ws + 1000 * 256 * sizeof(float2));
    float* partial = scores + NSCORES;                              // 32 floats
    float* out = (float*)d_out;

    rel_fft_kernel<<<dim3(1000), dim3(256), 0, stream>>>(rel, FrP);
    score_kernel<<<dim3(NSCORES / 16), dim3(256), 0, stream>>>(
        pos_h, pos_t, pos_r, neg_h, neg_t, neg_r, ent, FrP, scores);
    loss1_kernel<<<dim3(BATCH / 256), dim3(256), 0, stream>>>(scores, partial);
    loss2_kernel<<<dim3(1), dim3(64), 0, stream>>>(partial, out);
}

// Round 10
// 68.000 us; speedup vs baseline: 1.6938x; 1.1362x over previous
//
#include <hip/hip_runtime.h>
#include <math.h>

#define HIDDEN 256
#define BATCH 8192
#define NEGS 16
#define NSCORES (BATCH + BATCH * NEGS)  // 139264
#define PI2 6.28318530717958647692f

typedef unsigned int uint32;
typedef _Float16 h2v __attribute__((ext_vector_type(2)));

__device__ __forceinline__ float2 cmul(float2 a, float2 b) {
    return make_float2(fmaf(a.x, b.x, -a.y * b.y), fmaf(a.x, b.y, a.y * b.x));
}
__device__ __forceinline__ float2 cmulc(float2 a, float cx, float cy) {
    return make_float2(fmaf(a.x, cx, -a.y * cy), fmaf(a.x, cy, a.y * cx));
}
__device__ __forceinline__ float2 mulnegi(float2 a) { return make_float2(a.y, -a.x); }

__device__ __forceinline__ uint32 pk(float a, float b) {
    auto p = __builtin_amdgcn_cvt_pkrtz(a, b);
    uint32 u; __builtin_memcpy(&u, &p, 4);
    return u;
}
__device__ __forceinline__ float2 unpk(uint32 u) {
    h2v h; __builtin_memcpy(&h, &u, 4);
    return make_float2((float)h.x, (float)h.y);
}

// DPP cross-lane (VALU): quad_perm xor1=0xB1, xor2=0x4E, row_mirror=0x140
template<int C>
__device__ __forceinline__ float fdpp(float v) {
    return __uint_as_float((unsigned)__builtin_amdgcn_mov_dpp(
        (int)__float_as_uint(v), C, 0xf, 0xf, true));
}
// ds_swizzle: xor4=0x101F, xor8=0x201F
template<int IMM>
__device__ __forceinline__ float fswz(float v) {
    return __uint_as_float((unsigned)__builtin_amdgcn_ds_swizzle(
        (int)__float_as_uint(v), IMM));
}

// radix-4 DIF butterfly: u_k = DFT4 at freq k (W4 = -i)
__device__ __forceinline__ void bfly4(float2 a, float2 b, float2 c, float2 d,
                                      float2& u0, float2& u1, float2& u2, float2& u3) {
    float2 apc = make_float2(a.x + c.x, a.y + c.y);
    float2 amc = make_float2(a.x - c.x, a.y - c.y);
    float2 bpd = make_float2(b.x + d.x, b.y + d.y);
    float2 bmd = make_float2(b.x - d.x, b.y - d.y);
    u0 = make_float2(apc.x + bpd.x, apc.y + bpd.y);
    u2 = make_float2(apc.x - bpd.x, apc.y - bpd.y);
    u1 = make_float2(amc.x + bmd.y, amc.y - bmd.x);   // (a-c) - i(b-d)
    u3 = make_float2(amc.x - bmd.y, amc.y + bmd.x);   // (a-c) + i(b-d)
}

// In-register 16-point complex DFT (DIF radix-4), natural-order in/out.
__device__ __forceinline__ void fft16(float2 z[16]) {
    const float R  = 0.70710678118654752440f;
    const float C1 = 0.92387953251128675613f;
    const float S1 = 0.38268343236508977173f;
    #pragma unroll
    for (int p = 0; p < 4; ++p) {
        float2 u0, u1, u2, u3;
        bfly4(z[p], z[p+4], z[p+8], z[p+12], u0, u1, u2, u3);
        z[p] = u0; z[p+4] = u1; z[p+8] = u2; z[p+12] = u3;
    }
    z[5]  = cmulc(z[5],  C1, -S1);
    z[6]  = cmulc(z[6],  R,  -R );
    z[7]  = cmulc(z[7],  S1, -C1);
    z[9]  = cmulc(z[9],  R,  -R );
    z[10] = mulnegi(z[10]);
    z[11] = cmulc(z[11], -R, -R );
    z[13] = cmulc(z[13], S1, -C1);
    z[14] = cmulc(z[14], -R, -R );
    z[15] = cmulc(z[15], -C1, S1);
    float2 o[16];
    #pragma unroll
    for (int k = 0; k < 4; ++k) {
        float2 v0, v1, v2, v3;
        bfly4(z[4*k], z[4*k+1], z[4*k+2], z[4*k+3], v0, v1, v2, v3);
        o[k] = v0; o[k+4] = v1; o[k+8] = v2; o[k+12] = v3;
    }
    #pragma unroll
    for (int i = 0; i < 16; ++i) z[i] = o[i];
}

// twiddle z[f1] *= W256^{L*f1}, shallow-dependency (w4 decomposition)
__device__ __forceinline__ void twiddle256(float2 z[16], int L) {
    float s1, c1, s4, c4;
    __sincosf(-PI2 * (1.0f / 256.0f) * (float)L, &s1, &c1);
    __sincosf(-PI2 * (4.0f / 256.0f) * (float)L, &s4, &c4);
    const float2 w1 = make_float2(c1, s1);
    const float2 w4 = make_float2(c4, s4);
    const float2 w2 = cmul(w1, w1);
    const float2 w3 = cmul(w2, w1);
    const float2 w8 = cmul(w4, w4);
    const float2 w12 = cmul(w8, w4);
    float2 wp[16];
    wp[1] = w1; wp[2] = w2; wp[3] = w3;
    wp[4] = w4; wp[5] = cmul(w4, w1); wp[6] = cmul(w4, w2); wp[7] = cmul(w4, w3);
    wp[8] = w8; wp[9] = cmul(w8, w1); wp[10] = cmul(w8, w2); wp[11] = cmul(w8, w3);
    wp[12] = w12; wp[13] = cmul(w12, w1); wp[14] = cmul(w12, w2); wp[15] = cmul(w12, w3);
    #pragma unroll
    for (int f1 = 1; f1 < 16; ++f1) z[f1] = cmul(z[f1], wp[f1]);
}

// lane digit map: sig(15-L) = 16 - sig(L) (mod 16 for L=0/15 pair)
__device__ __forceinline__ int sigmap(int L) {
    return (L == 0) ? 0 : (L == 15 ? 8 : (L < 8 ? L : L + 1));
}

// ---------------- rel pre-FFT (four-step, 16 rows per block) ----------------
#define RRS 18                 // f32 transpose row stride (float2)
#define RGS (16 * RRS + 2)     // group stride 290 float2 (2320B, 16B-aligned)

__global__ __launch_bounds__(256) void rel_fft_kernel(
    const float* __restrict__ rel, float2* __restrict__ FrP)
{
    __shared__ __align__(16) float2 Tr[16 * RGS];   // ~37 KB
    const int tid = threadIdx.x;
    const int gb = tid >> 4;
    const int L = tid & 15;
    const int ri = blockIdx.x * 16 + gb;
    if (ri >= 1000) return;

    const float* __restrict__ rrow = rel + (long)ri * HIDDEN;
    float2 z[16];
    float rn2 = 0.f;
    #pragma unroll
    for (int n1 = 0; n1 < 16; ++n1) {
        const float v = rrow[16 * n1 + L];
        z[n1] = make_float2(v, 0.f);
        rn2 = fmaf(v, v, rn2);
    }
    // 16-lane reduce (butterfly -> all lanes)
    rn2 += fdpp<0xB1>(rn2);
    rn2 += fdpp<0x4E>(rn2);
    rn2 += fswz<0x101F>(rn2);
    rn2 += fswz<0x201F>(rn2);
    const float s = rsqrtf(fmaxf(rn2, 1e-12f)) * (1.0f / 256.0f);

    fft16(z);
    twiddle256(z, L);

    float2* __restrict__ Tg = Tr + gb * RGS;
    {
        float4* __restrict__ wp4 = (float4*)(Tg + L * RRS);
        #pragma unroll
        for (int j = 0; j < 8; ++j)
            wp4[j] = make_float4(z[2*j].x, z[2*j].y, z[2*j+1].x, z[2*j+1].y);
    }
    const int sig = sigmap(L);
    __builtin_amdgcn_wave_barrier();
    #pragma unroll
    for (int n2 = 0; n2 < 16; ++n2) z[n2] = Tg[n2 * RRS + sig];

    fft16(z);   // lane holds Fr[sig + 16*f2] in reg f2

    float2* __restrict__ ob = FrP + (long)ri * 256 + sig;
    #pragma unroll
    for (int f2 = 0; f2 < 16; ++f2)
        ob[16 * f2] = make_float2(z[f2].x * (s * 0.5f), z[f2].y * (s * 0.25f));
}

// ---------------- score kernel (f16-packed transpose) ----------------
#define RSU 20                 // uint row stride: 80B, 16B-aligned
#define GSU (16 * RSU + 4)     // 324 uints (1296B, 16B-aligned; bank rotate 4)

__global__ __launch_bounds__(256, 5) void score_kernel(
    const int* __restrict__ pos_h, const int* __restrict__ pos_t, const int* __restrict__ pos_r,
    const int* __restrict__ neg_h, const int* __restrict__ neg_t, const int* __restrict__ neg_r,
    const float* __restrict__ ent, const float2* __restrict__ FrP,
    float* __restrict__ scores)
{
    __shared__ __align__(16) uint32 Tu[16 * GSU];   // 20.7 KB
    const int tid = threadIdx.x;
    const int gb = tid >> 4;
    const int L = tid & 15;
    const int s = blockIdx.x * 16 + gb;

    const bool isp = s < BATCH;
    const int jj = isp ? s : s - BATCH;
    const int hi = (isp ? pos_h : neg_h)[jj];
    const int ti = (isp ? pos_t : neg_t)[jj];
    const int ri = (isp ? pos_r : neg_r)[jj];

    const float* __restrict__ hrow = ent + (long)hi * HIDDEN;
    const float* __restrict__ trow = ent + (long)ti * HIDDEN;

    float2 z[16];
    #pragma unroll
    for (int n1 = 0; n1 < 16; ++n1)
        z[n1] = make_float2(hrow[16 * n1 + L], trow[16 * n1 + L]);

    fft16(z);
    twiddle256(z, L);

    // transpose write: 4 x b128 of f16-packed (x,y)
    uint32* __restrict__ Tg = Tu + gb * GSU;
    {
        uint4* __restrict__ wp4 = (uint4*)(Tg + L * RSU);
        #pragma unroll
        for (int j = 0; j < 4; ++j)
            wp4[j] = make_uint4(pk(z[4*j].x,   z[4*j].y),
                                pk(z[4*j+1].x, z[4*j+1].y),
                                pk(z[4*j+2].x, z[4*j+2].y),
                                pk(z[4*j+3].x, z[4*j+3].y));
    }

    const int sig = sigmap(L);
    const float2* __restrict__ fb = FrP + (long)ri * 256 + sig;

    // first half of fr loads (in flight across fft2)
    float2 fr0[8];
    #pragma unroll
    for (int f2 = 0; f2 < 8; ++f2) fr0[f2] = fb[16 * f2];

    __builtin_amdgcn_wave_barrier();
    #pragma unroll
    for (int n2 = 0; n2 < 16; ++n2) z[n2] = unpk(Tg[n2 * RSU + sig]);

    fft16(z);   // Z[f2] = X[sig + 16 f2]

    // second half of fr loads (returns during first contraction iters)
    float2 fr1[8];
    #pragma unroll
    for (int f2 = 0; f2 < 8; ++f2) fr1[f2] = fb[16 * (f2 + 8)];

    const bool isL0 = (L == 0), isL15 = (L == 15);
    float S = 0.f;
    #pragma unroll
    for (int f2 = 0; f2 < 16; ++f2) {
        // partner of (lane, f2): mirror lane, reg 15-f2 (lanes 1..14);
        // lane 0: own reg (16-f2)&15; lane 15: own reg 15-f2.
        float2 src = z[15 - f2];
        float2 Bm = make_float2(fdpp<0x140>(src.x), fdpp<0x140>(src.y));
        float2 own0 = z[(16 - f2) & 15];
        float2 B;
        B.x = isL0 ? own0.x : (isL15 ? src.x : Bm.x);
        B.y = isL0 ? own0.y : (isL15 ? src.y : Bm.y);
        const float2 A = z[f2];
        const float2 fr = (f2 < 8) ? fr0[f2 & 7] : fr1[f2 & 7];
        const float imAB = A.x * B.y + A.y * B.x;
        const float dmag = (B.x * B.x + B.y * B.y) - (A.x * A.x + A.y * A.y);
        S = fmaf(fr.x, imAB, fmaf(fr.y, dmag, S));
    }

    // reduce across the 16-lane group
    S += fdpp<0xB1>(S);
    S += fdpp<0x4E>(S);
    S += fswz<0x101F>(S);
    S += fswz<0x201F>(S);

    if (L == 0) scores[s] = -1.0f / (1.0f + __expf(-S));
}

// Stage 1: 32 blocks x 256 threads -> partial[32]
__global__ __launch_bounds__(256) void loss1_kernel(
    const float* __restrict__ scores, float* __restrict__ partial)
{
    __shared__ float red[4];
    const int b = blockIdx.x * 256 + threadIdx.x;
    const float p = scores[b];
    const float* __restrict__ np = scores + BATCH + b * NEGS;
    float n = 0.f;
    #pragma unroll
    for (int j = 0; j < NEGS; ++j) n += np[j];
    n *= (1.0f / NEGS);
    float v = fmaxf(p - n + 1.0f, 0.0f);
    #pragma unroll
    for (int m = 32; m >= 1; m >>= 1) v += __shfl_xor(v, m);
    const int wave = threadIdx.x >> 6, lane = threadIdx.x & 63;
    if (lane == 0) red[wave] = v;
    __syncthreads();
    if (threadIdx.x == 0)
        partial[blockIdx.x] = (red[0] + red[1]) + (red[2] + red[3]);
}

// Stage 2: one wave sums 32 partials (deterministic, overwrites out[0]).
__global__ __launch_bounds__(64) void loss2_kernel(
    const float* __restrict__ partial, float* __restrict__ out)
{
    const int lane = threadIdx.x;
    float v = (lane < 32) ? partial[lane] : 0.f;
    #pragma unroll
    for (int m = 32; m >= 1; m >>= 1) v += __shfl_xor(v, m);
    if (lane == 0) out[0] = v;
}

extern "C" void kernel_launch(void* const* d_in, const int* in_sizes, int n_in,
                              void* d_out, int out_size, void* d_ws, size_t ws_size,
                              hipStream_t stream) {
    (void)in_sizes; (void)n_in; (void)out_size; (void)ws_size;
    const int* pos_h = (const int*)d_in[0];
    const int* pos_t = (const int*)d_in[1];
    const int* pos_r = (const int*)d_in[2];
    const int* neg_h = (const int*)d_in[3];
    const int* neg_t = (const int*)d_in[4];
    const int* neg_r = (const int*)d_in[5];
    const float* ent = (const float*)d_in[6];
    const float* rel = (const float*)d_in[7];

    float2* FrP = (float2*)d_ws;                                    // 2,048,000 B
    float* scores = (float*)((char*)d_ws + 1000 * 256 * sizeof(float2));
    float* partial = scores + NSCORES;                              // 32 floats
    float* out = (float*)d_out;

    rel_fft_kernel<<<dim3(63), dim3(256), 0, stream>>>(rel, FrP);
    score_kernel<<<dim3(NSCORES / 16), dim3(256), 0, stream>>>(
        pos_h, pos_t, pos_r, neg_h, neg_t, neg_r, ent, FrP, scores);
    loss1_kernel<<<dim3(BATCH / 256), dim3(256), 0, stream>>>(scores, partial);
    loss2_kernel<<<dim3(1), dim3(64), 0, stream>>>(partial, out);
}

// Round 11
// 62.892 us; speedup vs baseline: 1.8314x; 1.0812x over previous
//
#include <hip/hip_runtime.h>
#include <math.h>

#define HIDDEN 256
#define BATCH 8192
#define NEGS 16
#define NSCORES (BATCH + BATCH * NEGS)  // 139264
#define PI2 6.28318530717958647692f
#define FR_STRIDE 136                   // float2 per rel row (129 used)

typedef unsigned int uint32;
typedef _Float16 h2v __attribute__((ext_vector_type(2)));

__device__ __forceinline__ float2 cmul(float2 a, float2 b) {
    return make_float2(fmaf(a.x, b.x, -a.y * b.y), fmaf(a.x, b.y, a.y * b.x));
}
__device__ __forceinline__ float2 cmulc(float2 a, float cx, float cy) {
    return make_float2(fmaf(a.x, cx, -a.y * cy), fmaf(a.x, cy, a.y * cx));
}
__device__ __forceinline__ float2 mulnegi(float2 a) { return make_float2(a.y, -a.x); }

__device__ __forceinline__ uint32 pk(float a, float b) {
    auto p = __builtin_amdgcn_cvt_pkrtz(a, b);
    uint32 u; __builtin_memcpy(&u, &p, 4);
    return u;
}
__device__ __forceinline__ float2 unpk(uint32 u) {
    h2v h; __builtin_memcpy(&h, &u, 4);
    return make_float2((float)h.x, (float)h.y);
}

// DPP cross-lane (VALU): quad_perm xor1=0xB1, xor2=0x4E, row_mirror=0x140
template<int C>
__device__ __forceinline__ float fdpp(float v) {
    return __uint_as_float((unsigned)__builtin_amdgcn_mov_dpp(
        (int)__float_as_uint(v), C, 0xf, 0xf, true));
}
// ds_swizzle: xor4=0x101F, xor8=0x201F
template<int IMM>
__device__ __forceinline__ float fswz(float v) {
    return __uint_as_float((unsigned)__builtin_amdgcn_ds_swizzle(
        (int)__float_as_uint(v), IMM));
}

// radix-4 DIF butterfly: u_k = DFT4 at freq k (W4 = -i)
__device__ __forceinline__ void bfly4(float2 a, float2 b, float2 c, float2 d,
                                      float2& u0, float2& u1, float2& u2, float2& u3) {
    float2 apc = make_float2(a.x + c.x, a.y + c.y);
    float2 amc = make_float2(a.x - c.x, a.y - c.y);
    float2 bpd = make_float2(b.x + d.x, b.y + d.y);
    float2 bmd = make_float2(b.x - d.x, b.y - d.y);
    u0 = make_float2(apc.x + bpd.x, apc.y + bpd.y);
    u2 = make_float2(apc.x - bpd.x, apc.y - bpd.y);
    u1 = make_float2(amc.x + bmd.y, amc.y - bmd.x);   // (a-c) - i(b-d)
    u3 = make_float2(amc.x - bmd.y, amc.y + bmd.x);   // (a-c) + i(b-d)
}

// In-register 16-point complex DFT (DIF radix-4), natural-order in/out.
__device__ __forceinline__ void fft16(float2 z[16]) {
    const float R  = 0.70710678118654752440f;
    const float C1 = 0.92387953251128675613f;
    const float S1 = 0.38268343236508977173f;
    #pragma unroll
    for (int p = 0; p < 4; ++p) {
        float2 u0, u1, u2, u3;
        bfly4(z[p], z[p+4], z[p+8], z[p+12], u0, u1, u2, u3);
        z[p] = u0; z[p+4] = u1; z[p+8] = u2; z[p+12] = u3;
    }
    z[5]  = cmulc(z[5],  C1, -S1);
    z[6]  = cmulc(z[6],  R,  -R );
    z[7]  = cmulc(z[7],  S1, -C1);
    z[9]  = cmulc(z[9],  R,  -R );
    z[10] = mulnegi(z[10]);
    z[11] = cmulc(z[11], -R, -R );
    z[13] = cmulc(z[13], S1, -C1);
    z[14] = cmulc(z[14], -R, -R );
    z[15] = cmulc(z[15], -C1, S1);
    float2 o[16];
    #pragma unroll
    for (int k = 0; k < 4; ++k) {
        float2 v0, v1, v2, v3;
        bfly4(z[4*k], z[4*k+1], z[4*k+2], z[4*k+3], v0, v1, v2, v3);
        o[k] = v0; o[k+4] = v1; o[k+8] = v2; o[k+12] = v3;
    }
    #pragma unroll
    for (int i = 0; i < 16; ++i) z[i] = o[i];
}

// z[f1] *= W256^{L*f1} -- register-light (no wp[16] materialization)
__device__ __forceinline__ void twiddle256(float2 z[16], int L) {
    float s1, c1, s4, c4;
    __sincosf(-PI2 * (1.0f / 256.0f) * (float)L, &s1, &c1);
    __sincosf(-PI2 * (1.0f / 64.0f) * (float)L, &s4, &c4);
    const float2 w1 = make_float2(c1, s1);
    const float2 w4 = make_float2(c4, s4);
    const float2 w2 = cmul(w1, w1);
    const float2 w3 = cmul(w2, w1);
    z[1] = cmul(z[1], w1); z[2] = cmul(z[2], w2); z[3] = cmul(z[3], w3);
    float2 m = w4;
    #pragma unroll
    for (int a = 1; a < 4; ++a) {
        z[4*a]   = cmul(z[4*a], m);
        z[4*a+1] = cmul(cmul(z[4*a+1], m), w1);
        z[4*a+2] = cmul(cmul(z[4*a+2], m), w2);
        z[4*a+3] = cmul(cmul(z[4*a+3], m), w3);
        if (a < 3) m = cmul(m, w4);
    }
}

// lane digit map: sig(15-L) = 16 - sig(L) (mod 16 for L=0/15 pair)
__device__ __forceinline__ int sigmap(int L) {
    return (L == 0) ? 0 : (L == 15 ? 8 : (L < 8 ? L : L + 1));
}

// ---------------- rel pre-FFT (four-step, 16 rows per block) ----------------
// Emits the HALF table (r real => Fr[256-f] = conj Fr[f]):
//   slot f = sig + 16*f2 (f2<8): c = ( s*Re Fr_f , 0.5*s*Im Fr_f )   [pair f,256-f]
//   slot 0 fixup: c = ( 0.5*s*Re Fr_0 , 0 )   [self]
//   slot 128:     c = ( 0.5*s*Re Fr_128 , 0 ) [self, Nyquist]
// with s = 1/(256*||r||) and the original 1/2,1/4 factors folded in.
#define RRS 18
#define RGS (16 * RRS + 2)

__global__ __launch_bounds__(256) void rel_fft_kernel(
    const float* __restrict__ rel, float2* __restrict__ FrH)
{
    __shared__ __align__(16) float2 Tr[16 * RGS];
    const int tid = threadIdx.x;
    const int gb = tid >> 4;
    const int L = tid & 15;
    const int ri = blockIdx.x * 16 + gb;
    if (ri >= 1000) return;

    const float* __restrict__ rrow = rel + (long)ri * HIDDEN;
    float2 z[16];
    float rn2 = 0.f;
    #pragma unroll
    for (int n1 = 0; n1 < 16; ++n1) {
        const float v = rrow[16 * n1 + L];
        z[n1] = make_float2(v, 0.f);
        rn2 = fmaf(v, v, rn2);
    }
    rn2 += fdpp<0xB1>(rn2);
    rn2 += fdpp<0x4E>(rn2);
    rn2 += fswz<0x101F>(rn2);
    rn2 += fswz<0x201F>(rn2);
    const float s = rsqrtf(fmaxf(rn2, 1e-12f)) * (1.0f / 256.0f);

    fft16(z);
    twiddle256(z, L);

    float2* __restrict__ Tg = Tr + gb * RGS;
    {
        float4* __restrict__ wp4 = (float4*)(Tg + L * RRS);
        #pragma unroll
        for (int j = 0; j < 8; ++j)
            wp4[j] = make_float4(z[2*j].x, z[2*j].y, z[2*j+1].x, z[2*j+1].y);
    }
    const int sig = sigmap(L);
    __builtin_amdgcn_wave_barrier();
    #pragma unroll
    for (int n2 = 0; n2 < 16; ++n2) z[n2] = Tg[n2 * RRS + sig];

    fft16(z);   // lane holds Fr[sig + 16*f2] in reg f2

    float2* __restrict__ ob = FrH + (long)ri * FR_STRIDE + sig;
    #pragma unroll
    for (int f2 = 0; f2 < 8; ++f2) {
        float cx = s * z[f2].x;
        float cy = 0.5f * s * z[f2].y;
        if (sig == 0 && f2 == 0) { cx *= 0.5f; cy = 0.f; }
        ob[16 * f2] = make_float2(cx, cy);
    }
    if (L == 0)
        FrH[(long)ri * FR_STRIDE + 128] = make_float2(0.5f * s * z[8].x, 0.f);
}

// ---------------- score kernel ----------------
#define RSU 20                 // uint row stride: 80B, 16B-aligned
#define GSU (16 * RSU + 4)

__global__ __launch_bounds__(256, 6) void score_kernel(
    const int* __restrict__ pos_h, const int* __restrict__ pos_t, const int* __restrict__ pos_r,
    const int* __restrict__ neg_h, const int* __restrict__ neg_t, const int* __restrict__ neg_r,
    const float* __restrict__ ent, const float2* __restrict__ FrH,
    float* __restrict__ scores)
{
    __shared__ __align__(16) uint32 Tu[16 * GSU];   // 20.7 KB
    const int tid = threadIdx.x;
    const int gb = tid >> 4;
    const int L = tid & 15;
    const int s = blockIdx.x * 16 + gb;

    const bool isp = s < BATCH;
    const int jj = isp ? s : s - BATCH;
    const int hi = (isp ? pos_h : neg_h)[jj];
    const int ti = (isp ? pos_t : neg_t)[jj];
    const int ri = (isp ? pos_r : neg_r)[jj];

    const float* __restrict__ hrow = ent + (long)hi * HIDDEN;
    const float* __restrict__ trow = ent + (long)ti * HIDDEN;

    float2 z[16];
    #pragma unroll
    for (int n1 = 0; n1 < 16; ++n1)
        z[n1] = make_float2(hrow[16 * n1 + L], trow[16 * n1 + L]);

    fft16(z);
    twiddle256(z, L);

    // transpose write: 4 x b128 of f16-packed (x,y)
    uint32* __restrict__ Tg = Tu + gb * GSU;
    {
        uint4* __restrict__ wp4 = (uint4*)(Tg + L * RSU);
        #pragma unroll
        for (int j = 0; j < 4; ++j)
            wp4[j] = make_uint4(pk(z[4*j].x,   z[4*j].y),
                                pk(z[4*j+1].x, z[4*j+1].y),
                                pk(z[4*j+2].x, z[4*j+2].y),
                                pk(z[4*j+3].x, z[4*j+3].y));
    }

    const int sig = sigmap(L);

    __builtin_amdgcn_wave_barrier();
    #pragma unroll
    for (int n2 = 0; n2 < 16; ++n2) z[n2] = unpk(Tg[n2 * RSU + sig]);

    fft16(z);   // Z[f2] = X[sig + 16 f2]

    // half-table loads (after fft2: short liveness, L2-resident)
    const float2* __restrict__ fb = FrH + (long)ri * FR_STRIDE + sig;
    float2 fr[8];
    #pragma unroll
    for (int f2 = 0; f2 < 8; ++f2) fr[f2] = fb[16 * f2];
    const float2 c128 = FrH[(long)ri * FR_STRIDE + 128];

    const bool isL0 = (L == 0), isL15 = (L == 15);
    float S = 0.f;
    #pragma unroll
    for (int f2 = 0; f2 < 8; ++f2) {
        // partner of (lane, f2): mirror lane, reg 15-f2 (lanes 1..14);
        // lane 0: own reg (16-f2)&15; lane 15: own reg 15-f2.
        float2 src = z[15 - f2];
        float2 Bm = make_float2(fdpp<0x140>(src.x), fdpp<0x140>(src.y));
        float2 own0 = z[(16 - f2) & 15];
        float2 B;
        B.x = isL0 ? own0.x : (isL15 ? src.x : Bm.x);
        B.y = isL0 ? own0.y : (isL15 ? src.y : Bm.y);
        const float2 A = z[f2];
        const float imAB = A.x * B.y + A.y * B.x;
        const float dmag = (B.x * B.x + B.y * B.y) - (A.x * A.x + A.y * A.y);
        S = fmaf(fr[f2].x, imAB, fmaf(fr[f2].y, dmag, S));
    }
    // Nyquist self-bin (f=128 lives at lane sig=0, reg 8)
    if (isL0) S = fmaf(c128.x, 2.f * z[8].x * z[8].y, S);

    // reduce across the 16-lane group
    S += fdpp<0xB1>(S);
    S += fdpp<0x4E>(S);
    S += fswz<0x101F>(S);
    S += fswz<0x201F>(S);

    if (L == 0) scores[s] = -1.0f / (1.0f + __expf(-S));
}

// Stage 1: 32 blocks x 256 threads -> partial[32]
__global__ __launch_bounds__(256) void loss1_kernel(
    const float* __restrict__ scores, float* __restrict__ partial)
{
    __shared__ float red[4];
    const int b = blockIdx.x * 256 + threadIdx.x;
    const float p = scores[b];
    const float* __restrict__ np = scores + BATCH + b * NEGS;
    float n = 0.f;
    #pragma unroll
    for (int j = 0; j < NEGS; ++j) n += np[j];
    n *= (1.0f / NEGS);
    float v = fmaxf(p - n + 1.0f, 0.0f);
    #pragma unroll
    for (int m = 32; m >= 1; m >>= 1) v += __shfl_xor(v, m);
    const int wave = threadIdx.x >> 6, lane = threadIdx.x & 63;
    if (lane == 0) red[wave] = v;
    __syncthreads();
    if (threadIdx.x == 0)
        partial[blockIdx.x] = (red[0] + red[1]) + (red[2] + red[3]);
}

// Stage 2: one wave sums 32 partials (deterministic, overwrites out[0]).
__global__ __launch_bounds__(64) void loss2_kernel(
    const float* __restrict__ partial, float* __restrict__ out)
{
    const int lane = threadIdx.x;
    float v = (lane < 32) ? partial[lane] : 0.f;
    #pragma unroll
    for (int m = 32; m >= 1; m >>= 1) v += __shfl_xor(v, m);
    if (lane == 0) out[0] = v;
}

extern "C" void kernel_launch(void* const* d_in, const int* in_sizes, int n_in,
                              void* d_out, int out_size, void* d_ws, size_t ws_size,
                              hipStream_t stream) {
    (void)in_sizes; (void)n_in; (void)out_size; (void)ws_size;
    const int* pos_h = (const int*)d_in[0];
    const int* pos_t = (const int*)d_in[1];
    const int* pos_r = (const int*)d_in[2];
    const int* neg_h = (const int*)d_in[3];
    const int* neg_t = (const int*)d_in[4];
    const int* neg_r = (const int*)d_in[5];
    const float* ent = (const float*)d_in[6];
    const float* rel = (const float*)d_in[7];

    float2* FrH = (float2*)d_ws;                                    // 1000*136*8 = 1,088,000 B
    float* scores = (float*)((char*)d_ws + 1000 * FR_STRIDE * sizeof(float2));
    float* partial = scores + NSCORES;                              // 32 floats
    float* out = (float*)d_out;

    rel_fft_kernel<<<dim3(63), dim3(256), 0, stream>>>(rel, FrH);
    score_kernel<<<dim3(NSCORES / 16), dim3(256), 0, stream>>>(
        pos_h, pos_t, pos_r, neg_h, neg_t, neg_r, ent, FrH, scores);
    loss1_kernel<<<dim3(BATCH / 256), dim3(256), 0, stream>>>(scores, partial);
    loss2_kernel<<<dim3(1), dim3(64), 0, stream>>>(partial, out);
}

// Round 12
// 60.928 us; speedup vs baseline: 1.8904x; 1.0322x over previous
//
#include <hip/hip_runtime.h>
#include <math.h>

#define HIDDEN 256
#define BATCH 8192
#define NEGS 16
#define NSCORES (BATCH + BATCH * NEGS)  // 139264
#define PI2 6.28318530717958647692f
#define FR_STRIDE 136                   // float2 per rel row (129 used)

typedef unsigned int uint32;
typedef _Float16 h2v __attribute__((ext_vector_type(2)));

__device__ __forceinline__ float2 cmul(float2 a, float2 b) {
    return make_float2(fmaf(a.x, b.x, -a.y * b.y), fmaf(a.x, b.y, a.y * b.x));
}
__device__ __forceinline__ float2 cmulc(float2 a, float cx, float cy) {
    return make_float2(fmaf(a.x, cx, -a.y * cy), fmaf(a.x, cy, a.y * cx));
}
__device__ __forceinline__ float2 mulnegi(float2 a) { return make_float2(a.y, -a.x); }

__device__ __forceinline__ uint32 pk(float a, float b) {
    auto p = __builtin_amdgcn_cvt_pkrtz(a, b);
    uint32 u; __builtin_memcpy(&u, &p, 4);
    return u;
}
__device__ __forceinline__ float2 unpk(uint32 u) {
    h2v h; __builtin_memcpy(&h, &u, 4);
    return make_float2((float)h.x, (float)h.y);
}

// DPP cross-lane (VALU): quad_perm xor1=0xB1, xor2=0x4E, row_mirror=0x140
template<int C>
__device__ __forceinline__ float fdpp(float v) {
    return __uint_as_float((unsigned)__builtin_amdgcn_mov_dpp(
        (int)__float_as_uint(v), C, 0xf, 0xf, true));
}
// ds_swizzle: xor4=0x101F, xor8=0x201F
template<int IMM>
__device__ __forceinline__ float fswz(float v) {
    return __uint_as_float((unsigned)__builtin_amdgcn_ds_swizzle(
        (int)__float_as_uint(v), IMM));
}

// radix-4 DIF butterfly: u_k = DFT4 at freq k (W4 = -i)
__device__ __forceinline__ void bfly4(float2 a, float2 b, float2 c, float2 d,
                                      float2& u0, float2& u1, float2& u2, float2& u3) {
    float2 apc = make_float2(a.x + c.x, a.y + c.y);
    float2 amc = make_float2(a.x - c.x, a.y - c.y);
    float2 bpd = make_float2(b.x + d.x, b.y + d.y);
    float2 bmd = make_float2(b.x - d.x, b.y - d.y);
    u0 = make_float2(apc.x + bpd.x, apc.y + bpd.y);
    u2 = make_float2(apc.x - bpd.x, apc.y - bpd.y);
    u1 = make_float2(amc.x + bmd.y, amc.y - bmd.x);   // (a-c) - i(b-d)
    u3 = make_float2(amc.x - bmd.y, amc.y + bmd.x);   // (a-c) + i(b-d)
}

// In-register 16-point complex DFT (DIF radix-4), natural-order in/out.
__device__ __forceinline__ void fft16(float2 z[16]) {
    const float R  = 0.70710678118654752440f;
    const float C1 = 0.92387953251128675613f;
    const float S1 = 0.38268343236508977173f;
    #pragma unroll
    for (int p = 0; p < 4; ++p) {
        float2 u0, u1, u2, u3;
        bfly4(z[p], z[p+4], z[p+8], z[p+12], u0, u1, u2, u3);
        z[p] = u0; z[p+4] = u1; z[p+8] = u2; z[p+12] = u3;
    }
    z[5]  = cmulc(z[5],  C1, -S1);
    z[6]  = cmulc(z[6],  R,  -R );
    z[7]  = cmulc(z[7],  S1, -C1);
    z[9]  = cmulc(z[9],  R,  -R );
    z[10] = mulnegi(z[10]);
    z[11] = cmulc(z[11], -R, -R );
    z[13] = cmulc(z[13], S1, -C1);
    z[14] = cmulc(z[14], -R, -R );
    z[15] = cmulc(z[15], -C1, S1);
    float2 o[16];
    #pragma unroll
    for (int k = 0; k < 4; ++k) {
        float2 v0, v1, v2, v3;
        bfly4(z[4*k], z[4*k+1], z[4*k+2], z[4*k+3], v0, v1, v2, v3);
        o[k] = v0; o[k+4] = v1; o[k+8] = v2; o[k+12] = v3;
    }
    #pragma unroll
    for (int i = 0; i < 16; ++i) z[i] = o[i];
}

// z[f1] *= W256^{L*f1} -- register-light
__device__ __forceinline__ void twiddle256(float2 z[16], int L) {
    float s1, c1, s4, c4;
    __sincosf(-PI2 * (1.0f / 256.0f) * (float)L, &s1, &c1);
    __sincosf(-PI2 * (1.0f / 64.0f) * (float)L, &s4, &c4);
    const float2 w1 = make_float2(c1, s1);
    const float2 w4 = make_float2(c4, s4);
    const float2 w2 = cmul(w1, w1);
    const float2 w3 = cmul(w2, w1);
    z[1] = cmul(z[1], w1); z[2] = cmul(z[2], w2); z[3] = cmul(z[3], w3);
    float2 m = w4;
    #pragma unroll
    for (int a = 1; a < 4; ++a) {
        z[4*a]   = cmul(z[4*a], m);
        z[4*a+1] = cmul(cmul(z[4*a+1], m), w1);
        z[4*a+2] = cmul(cmul(z[4*a+2], m), w2);
        z[4*a+3] = cmul(cmul(z[4*a+3], m), w3);
        if (a < 3) m = cmul(m, w4);
    }
}

// lane digit map: sig(15-L) = 16 - sig(L) (mod 16 for L=0/15 pair)
__device__ __forceinline__ int sigmap(int L) {
    return (L == 0) ? 0 : (L == 15 ? 8 : (L < 8 ? L : L + 1));
}

// ---------------- rel pre-FFT (four-step, 16 rows per block) ----------------
// Emits the HALF table (r real => Fr[256-f] = conj Fr[f]); see R11 comment.
#define RRS 18
#define RGS (16 * RRS + 2)

__global__ __launch_bounds__(256) void rel_fft_kernel(
    const float* __restrict__ rel, float2* __restrict__ FrH)
{
    __shared__ __align__(16) float2 Tr[16 * RGS];
    const int tid = threadIdx.x;
    const int gb = tid >> 4;
    const int L = tid & 15;
    const int ri = blockIdx.x * 16 + gb;
    if (ri >= 1000) return;

    const float* __restrict__ rrow = rel + (long)ri * HIDDEN;
    float2 z[16];
    float rn2 = 0.f;
    #pragma unroll
    for (int n1 = 0; n1 < 16; ++n1) {
        const float v = rrow[16 * n1 + L];
        z[n1] = make_float2(v, 0.f);
        rn2 = fmaf(v, v, rn2);
    }
    rn2 += fdpp<0xB1>(rn2);
    rn2 += fdpp<0x4E>(rn2);
    rn2 += fswz<0x101F>(rn2);
    rn2 += fswz<0x201F>(rn2);
    const float s = rsqrtf(fmaxf(rn2, 1e-12f)) * (1.0f / 256.0f);

    fft16(z);
    twiddle256(z, L);

    float2* __restrict__ Tg = Tr + gb * RGS;
    {
        float4* __restrict__ wp4 = (float4*)(Tg + L * RRS);
        #pragma unroll
        for (int j = 0; j < 8; ++j)
            wp4[j] = make_float4(z[2*j].x, z[2*j].y, z[2*j+1].x, z[2*j+1].y);
    }
    const int sig = sigmap(L);
    __builtin_amdgcn_wave_barrier();
    #pragma unroll
    for (int n2 = 0; n2 < 16; ++n2) z[n2] = Tg[n2 * RRS + sig];

    fft16(z);   // lane holds Fr[sig + 16*f2] in reg f2

    float2* __restrict__ ob = FrH + (long)ri * FR_STRIDE + sig;
    #pragma unroll
    for (int f2 = 0; f2 < 8; ++f2) {
        float cx = s * z[f2].x;
        float cy = 0.5f * s * z[f2].y;
        if (sig == 0 && f2 == 0) { cx *= 0.5f; cy = 0.f; }
        ob[16 * f2] = make_float2(cx, cy);
    }
    if (L == 0)
        FrH[(long)ri * FR_STRIDE + 128] = make_float2(0.5f * s * z[8].x, 0.f);
}

// ---------------- score kernel (folds neg-mean per batch row) ----------------
// Blocks 0..511: 16 positive scores -> p[s]. Blocks 512..8703: the 16 negatives
// of batch row (blk-512) -> nmean[row] (deterministic serial 16-sum by tid 0).
#define RSU 20
#define GSU (16 * RSU + 4)

__global__ __launch_bounds__(256, 6) void score_kernel(
    const int* __restrict__ pos_h, const int* __restrict__ pos_t, const int* __restrict__ pos_r,
    const int* __restrict__ neg_h, const int* __restrict__ neg_t, const int* __restrict__ neg_r,
    const float* __restrict__ ent, const float2* __restrict__ FrH,
    float* __restrict__ p_out, float* __restrict__ nmean_out)
{
    __shared__ __align__(16) uint32 Tu[16 * GSU];   // 20.7 KB
    __shared__ float nbuf[16];
    const int tid = threadIdx.x;
    const int gb = tid >> 4;
    const int L = tid & 15;
    const int s = blockIdx.x * 16 + gb;

    const bool isp = s < BATCH;
    const int jj = isp ? s : s - BATCH;
    const int hi = (isp ? pos_h : neg_h)[jj];
    const int ti = (isp ? pos_t : neg_t)[jj];
    const int ri = (isp ? pos_r : neg_r)[jj];

    const float* __restrict__ hrow = ent + (long)hi * HIDDEN;
    const float* __restrict__ trow = ent + (long)ti * HIDDEN;

    float2 z[16];
    #pragma unroll
    for (int n1 = 0; n1 < 16; ++n1)
        z[n1] = make_float2(hrow[16 * n1 + L], trow[16 * n1 + L]);

    fft16(z);
    twiddle256(z, L);

    uint32* __restrict__ Tg = Tu + gb * GSU;
    {
        uint4* __restrict__ wp4 = (uint4*)(Tg + L * RSU);
        #pragma unroll
        for (int j = 0; j < 4; ++j)
            wp4[j] = make_uint4(pk(z[4*j].x,   z[4*j].y),
                                pk(z[4*j+1].x, z[4*j+1].y),
                                pk(z[4*j+2].x, z[4*j+2].y),
                                pk(z[4*j+3].x, z[4*j+3].y));
    }

    const int sig = sigmap(L);

    __builtin_amdgcn_wave_barrier();
    #pragma unroll
    for (int n2 = 0; n2 < 16; ++n2) z[n2] = unpk(Tg[n2 * RSU + sig]);

    fft16(z);   // Z[f2] = X[sig + 16 f2]

    const float2* __restrict__ fb = FrH + (long)ri * FR_STRIDE + sig;
    float2 fr[8];
    #pragma unroll
    for (int f2 = 0; f2 < 8; ++f2) fr[f2] = fb[16 * f2];
    const float2 c128 = FrH[(long)ri * FR_STRIDE + 128];

    const bool isL0 = (L == 0), isL15 = (L == 15);
    float S = 0.f;
    #pragma unroll
    for (int f2 = 0; f2 < 8; ++f2) {
        float2 src = z[15 - f2];
        float2 Bm = make_float2(fdpp<0x140>(src.x), fdpp<0x140>(src.y));
        float2 own0 = z[(16 - f2) & 15];
        float2 B;
        B.x = isL0 ? own0.x : (isL15 ? src.x : Bm.x);
        B.y = isL0 ? own0.y : (isL15 ? src.y : Bm.y);
        const float2 A = z[f2];
        const float imAB = A.x * B.y + A.y * B.x;
        const float dmag = (B.x * B.x + B.y * B.y) - (A.x * A.x + A.y * A.y);
        S = fmaf(fr[f2].x, imAB, fmaf(fr[f2].y, dmag, S));
    }
    if (isL0) S = fmaf(c128.x, 2.f * z[8].x * z[8].y, S);

    // reduce across the 16-lane group
    S += fdpp<0xB1>(S);
    S += fdpp<0x4E>(S);
    S += fswz<0x101F>(S);
    S += fswz<0x201F>(S);

    if (isp) {
        if (L == 0) p_out[s] = -1.0f / (1.0f + __expf(-S));
    } else {
        if (L == 0) nbuf[gb] = -1.0f / (1.0f + __expf(-S));
        __syncthreads();
        if (tid == 0) {
            float n = 0.f;
            #pragma unroll
            for (int i = 0; i < 16; ++i) n += nbuf[i];
            nmean_out[blockIdx.x - BATCH / 16] = n * (1.0f / NEGS);
        }
    }
}

// Single-block loss: reads p[8192] + nmean[8192] (64 KB), overwrites out[0].
__global__ __launch_bounds__(1024) void loss_kernel(
    const float* __restrict__ p, const float* __restrict__ nmean,
    float* __restrict__ out)
{
    __shared__ float red[16];
    float v = 0.f;
    #pragma unroll
    for (int k = 0; k < BATCH / 1024; ++k) {
        const int b = threadIdx.x + 1024 * k;
        v += fmaxf(p[b] - nmean[b] + 1.0f, 0.0f);
    }
    #pragma unroll
    for (int m = 32; m >= 1; m >>= 1) v += __shfl_xor(v, m);
    const int wave = threadIdx.x >> 6, lane = threadIdx.x & 63;
    if (lane == 0) red[wave] = v;
    __syncthreads();
    if (threadIdx.x < 16) {
        float w = red[threadIdx.x];
        #pragma unroll
        for (int m = 8; m >= 1; m >>= 1) w += __shfl_xor(w, m, 16);
        if (threadIdx.x == 0) out[0] = w;
    }
}

extern "C" void kernel_launch(void* const* d_in, const int* in_sizes, int n_in,
                              void* d_out, int out_size, void* d_ws, size_t ws_size,
                              hipStream_t stream) {
    (void)in_sizes; (void)n_in; (void)out_size; (void)ws_size;
    const int* pos_h = (const int*)d_in[0];
    const int* pos_t = (const int*)d_in[1];
    const int* pos_r = (const int*)d_in[2];
    const int* neg_h = (const int*)d_in[3];
    const int* neg_t = (const int*)d_in[4];
    const int* neg_r = (const int*)d_in[5];
    const float* ent = (const float*)d_in[6];
    const float* rel = (const float*)d_in[7];

    float2* FrH = (float2*)d_ws;                                    // 1,088,000 B
    float* p = (float*)((char*)d_ws + 1000 * FR_STRIDE * sizeof(float2));
    float* nmean = p + BATCH;
    float* out = (float*)d_out;

    rel_fft_kernel<<<dim3(63), dim3(256), 0, stream>>>(rel, FrH);
    score_kernel<<<dim3(NSCORES / 16), dim3(256), 0, stream>>>(
        pos_h, pos_t, pos_r, neg_h, neg_t, neg_r, ent, FrH, p, nmean);
    loss_kernel<<<dim3(1), dim3(1024), 0, stream>>>(p, nmean, out);
}